// Round 14
// baseline (190.046 us; speedup 1.0000x reference)
//
#include <hip/hip_runtime.h>
#include <hip/hip_bf16.h>

#define D 64
#define MARGIN 4e-5f
#define KS 2          // k-split factor across blocks

typedef __attribute__((ext_vector_type(8))) short bf16x8;
typedef __attribute__((ext_vector_type(4))) float f32x4;
typedef __attribute__((ext_vector_type(4))) unsigned uint4v;

// ---------------------------------------------------------------------------
// VectorQuantizer. Harness ref = numpy-f32 recompute; argmin must bit-match
// np-f32 (xx pairwise-8 sum, sequential-d FMA sgemm, first-min). Screen is a
// split-bf16 MFMA proxy: acc = dot - ee/2 (6-MFMA chain seeded C = -ee/2),
// argmax(acc) == argmin(dist). Codes tile-major pre-permuted, LDS-staged
// double-buffered (T14 split) -> 1 VMEM/wave/tile. Screen emits per-slice
// (m1,m2,bi) SoA planes + xxp. vq_epilogue (2048 blocks x 64 rows): decide
// (ascending slice + strict > == np first-min, margin test), idx, block-
// partial loss -> lossA[] (PLAIN STORE — no fp atomics: HIP fp atomicAdd is
// a CAS loop and 3.5K same-address CAS cost ~85us in R13), ambiguous-row
// list via one u32 atomic per block (ballot+rank), coalesced quantized
// write. vq_resolve: one WAVE per ambiguous row (np-f32-exact, eT-coalesced,
// ascending-index merges == np first-min), loss -> lossR[]. vq_histperp:
// LDS hist of outidx + last-block reduce(lossA,lossR) + perplexity/loss.
// d_out (float): quantized[N*D] | loss[1] | indices[N] | perplexity[1]
// ws: counts u32[K] | done u32 | nunc u32 | pad | neh f32[K] | eenp f32[K]
//     | ehs bf16-tiles[K*256B] | eT f32[D*K]
//     | m1p f32[KS*N] | m2p f32[KS*N] | bip i32[KS*N] | xxp f32[N]
//     | list u32[N] | lossA f64[2048] | lossR f64[1024]
// ---------------------------------------------------------------------------

__device__ __forceinline__ float np_pairwise_sumsq64(const float* a) {
    float r[8];
#pragma unroll
    for (int j = 0; j < 8; ++j) r[j] = __fmul_rn(a[j], a[j]);
#pragma unroll
    for (int i = 8; i < 64; i += 8)
#pragma unroll
        for (int j = 0; j < 8; ++j)
            r[j] = __fadd_rn(r[j], __fmul_rn(a[i + j], a[i + j]));
    return __fadd_rn(
        __fadd_rn(__fadd_rn(r[0], r[1]), __fadd_rn(r[2], r[3])),
        __fadd_rn(__fadd_rn(r[4], r[5]), __fadd_rn(r[6], r[7])));
}

#define CVT8(F0, F1, H, L)                                                    \
    do {                                                                      \
        float _f[8] = {F0.x, F0.y, F0.z, F0.w, F1.x, F1.y, F1.z, F1.w};       \
        _Pragma("unroll") for (int _i = 0; _i < 8; ++_i) {                    \
            unsigned _u = __float_as_uint(_f[_i]);                            \
            unsigned _hb = (_u + 0x7fffu + ((_u >> 16) & 1u)) >> 16;          \
            float _hf = __uint_as_float(_hb << 16);                           \
            float _r = _f[_i] - _hf;                                          \
            unsigned _u2 = __float_as_uint(_r);                               \
            unsigned _lb = (_u2 + 0x7fffu + ((_u2 >> 16) & 1u)) >> 16;        \
            H[_i] = (short)_hb;                                               \
            L[_i] = (short)_lb;                                               \
        }                                                                     \
    } while (0)

// prep: blocks [0,64) build ehs tile-major; [64,68) sumsq; [68,324) eT
__global__ __launch_bounds__(256) void vq_prep_all(
    const float* __restrict__ emb, int K,
    float* __restrict__ eenp, float* __restrict__ neh,
    unsigned short* __restrict__ ehs, float* __restrict__ eT) {
    int b = blockIdx.x;
    if (b < 64) {
        int t = b * 256 + threadIdx.x;     // (tile, sec, lane): 16384 frags
        int tile = t >> 8, r = t & 255, s = r >> 6, l = r & 63;
        int sub = l & 15, grp = l >> 4;
        int k = tile * 16 + sub;
        int d0 = ((s & 1) << 5) + (grp << 3);
        const float* e = emb + (size_t)k * D + d0;
        float4 f0 = *(const float4*)e;
        float4 f1 = *(const float4*)(e + 4);
        bf16x8 h, lo;
        CVT8(f0, f1, h, lo);
        *(bf16x8*)(ehs + (size_t)t * 8) = (s >> 1) ? lo : h;  // s0,s1=eh s2,s3=el
    } else if (b < 68) {
        int k = (b - 64) * 256 + threadIdx.x;   // 1024 codes
        float s = np_pairwise_sumsq64(emb + (size_t)k * D);
        eenp[k] = s;
        neh[k] = -0.5f * s;
    } else {
        int t = (b - 68) * 256 + threadIdx.x;   // 65536 = D*K, coalesced write
        int d = t / K, k = t - d * K;
        eT[t] = emb[(size_t)k * D + d];
    }
}

__global__ __launch_bounds__(256) void vq_screen(
    const float* __restrict__ x, const unsigned short* __restrict__ ehs,
    const float* __restrict__ neh, int N, int K,
    float* __restrict__ m1p, float* __restrict__ m2p, int* __restrict__ bip,
    float* __restrict__ xxp) {
    const int tid = threadIdx.x;
    const int lane = tid & 63;
    const int wid = tid >> 6;
    const int kslice = blockIdx.x & (KS - 1);
    const int rowblk = blockIdx.x >> 1;  // KS == 2
    const int row0 = rowblk * 256 + wid * 64;  // 64 rows/wave
    const int sub = lane & 15, grp = lane >> 4;
    const int g4 = grp << 2;
    const int k0 = kslice * (K / KS);
    const int NT = (K / KS) >> 4;        // 16-code tiles in this slice
    const int t0 = k0 >> 4;

    __shared__ __align__(16) unsigned short lds[2][2048];  // 2 bufs x 4KB

    // persistent B frags: x rows, split bf16, 4 row-tiles x 2 k-slices.
    // Also accumulate per-lane sumsq (loss-only, f32) and grp-reduce -> xx.
    bf16x8 xh[4][2], xl[4][2];
    float xq[4];
#pragma unroll
    for (int rt = 0; rt < 4; ++rt) {
        xq[rt] = 0.f;
        const float* xrow = x + (((size_t)(row0 + (rt << 4) + sub)) << 6) + (grp << 3);
#pragma unroll
        for (int s = 0; s < 2; ++s) {
            float4 f0 = *(const float4*)(xrow + (s << 5));
            float4 f1 = *(const float4*)(xrow + (s << 5) + 4);
            xq[rt] = fmaf(f0.x, f0.x, xq[rt]); xq[rt] = fmaf(f0.y, f0.y, xq[rt]);
            xq[rt] = fmaf(f0.z, f0.z, xq[rt]); xq[rt] = fmaf(f0.w, f0.w, xq[rt]);
            xq[rt] = fmaf(f1.x, f1.x, xq[rt]); xq[rt] = fmaf(f1.y, f1.y, xq[rt]);
            xq[rt] = fmaf(f1.z, f1.z, xq[rt]); xq[rt] = fmaf(f1.w, f1.w, xq[rt]);
            CVT8(f0, f1, xh[rt][s], xl[rt][s]);
        }
    }
#pragma unroll
    for (int rt = 0; rt < 4; ++rt) {
        xq[rt] += __shfl_xor(xq[rt], 16);
        xq[rt] += __shfl_xor(xq[rt], 32);  // all grps summed; lane<16 = row xx
    }

    float m1[4], m2[4];
    int bi[4];
#pragma unroll
    for (int rt = 0; rt < 4; ++rt) { m1[rt] = -3e38f; m2[rt] = -3e38f; bi[rt] = 0; }

    // staging: this thread's 16B slot (wave wid stages section wid)
    const unsigned short* sbase = ehs + ((size_t)t0 << 11);  // tile stride 2048 ush
    const int slot = (wid << 9) + (lane << 3);               // ushort offset

    uint4v tmp = *(const uint4v*)(sbase + slot);             // tile 0
    *(uint4v*)&lds[0][slot] = tmp;
    __syncthreads();

    for (int t = 0; t < NT; ++t) {
        const int cur = t & 1;
        if (t + 1 < NT)  // T14: issue next-tile load before compute
            tmp = *(const uint4v*)(sbase + ((size_t)(t + 1) << 11) + slot);

        f32x4 cb = *(const f32x4*)(neh + k0 + (t << 4) + g4);
        const bf16x8* L = (const bf16x8*)&lds[cur][0];
        bf16x8 a0 = L[lane];        // eh d[0,32)
        bf16x8 a1 = L[64 + lane];   // eh d[32,64)
        bf16x8 a2 = L[128 + lane];  // el d[0,32)
        bf16x8 a3 = L[192 + lane];  // el d[32,64)

        f32x4 acc[4];
#pragma unroll
        for (int rt = 0; rt < 4; ++rt)
            acc[rt] = __builtin_amdgcn_mfma_f32_16x16x32_bf16(a0, xh[rt][0], cb, 0, 0, 0);
#pragma unroll
        for (int rt = 0; rt < 4; ++rt)
            acc[rt] = __builtin_amdgcn_mfma_f32_16x16x32_bf16(a2, xh[rt][0], acc[rt], 0, 0, 0);
#pragma unroll
        for (int rt = 0; rt < 4; ++rt)
            acc[rt] = __builtin_amdgcn_mfma_f32_16x16x32_bf16(a0, xl[rt][0], acc[rt], 0, 0, 0);
#pragma unroll
        for (int rt = 0; rt < 4; ++rt)
            acc[rt] = __builtin_amdgcn_mfma_f32_16x16x32_bf16(a1, xh[rt][1], acc[rt], 0, 0, 0);
#pragma unroll
        for (int rt = 0; rt < 4; ++rt)
            acc[rt] = __builtin_amdgcn_mfma_f32_16x16x32_bf16(a3, xh[rt][1], acc[rt], 0, 0, 0);
#pragma unroll
        for (int rt = 0; rt < 4; ++rt)
            acc[rt] = __builtin_amdgcn_mfma_f32_16x16x32_bf16(a1, xl[rt][1], acc[rt], 0, 0, 0);

        // top-2 update; per-lane codes ascend -> np first-min
        int cbase = k0 + (t << 4) + g4;
#pragma unroll
        for (int rt = 0; rt < 4; ++rt) {
#pragma unroll
            for (int j = 0; j < 4; ++j) {
                float v = acc[rt][j];
                int c = cbase + j;
                bool tk = v > m1[rt];
                m2[rt] = fminf(fmaxf(v, m2[rt]), m1[rt]);  // med3(v,m2,m1)
                m1[rt] = tk ? v : m1[rt];
                bi[rt] = tk ? c : bi[rt];
            }
        }

        if (t + 1 < NT)  // T14: write-late into the other buffer
            *(uint4v*)&lds[cur ^ 1][slot] = tmp;
        __syncthreads();
    }

    // merge the 4 code-groups (lanes sub, sub+16, sub+32, sub+48)
#pragma unroll
    for (int rt = 0; rt < 4; ++rt) {
#pragma unroll
        for (int off = 16; off <= 32; off <<= 1) {
            float om1 = __shfl_xor(m1[rt], off);
            float om2 = __shfl_xor(m2[rt], off);
            int obi = __shfl_xor(bi[rt], off);
            bool take = (om1 > m1[rt]) || (om1 == m1[rt] && obi < bi[rt]);
            m2[rt] = fmaxf(fminf(om1, m1[rt]), fmaxf(om2, m2[rt]));
            m1[rt] = take ? om1 : m1[rt];
            bi[rt] = take ? obi : bi[rt];
        }
    }

    // emit coalesced SoA planes (lanes 0-15 own 16 consecutive rows per rt)
    if (lane < 16) {
#pragma unroll
        for (int rt = 0; rt < 4; ++rt) {
            size_t idx = (size_t)kslice * N + row0 + (rt << 4) + lane;
            m1p[idx] = m1[rt];
            m2p[idx] = m2[rt];
            bip[idx] = bi[rt];
            if (kslice == 0) xxp[row0 + (rt << 4) + lane] = xq[rt];
        }
    }
}

// decide + idx + block-partial loss (plain store) + coalesced quantized write
__global__ __launch_bounds__(256) void vq_epilogue(
    const float* __restrict__ emb,
    const float* __restrict__ m1p, const float* __restrict__ m2p,
    const int* __restrict__ bip, const float* __restrict__ xxp, int N,
    float* __restrict__ outq, float* __restrict__ outidx,
    double* __restrict__ lossA,
    unsigned* __restrict__ nunc, unsigned* __restrict__ list) {
    const int tid = threadIdx.x;
    const int rows0 = blockIdx.x * 64;
    __shared__ int sdec[64];

    if (tid < 64) {  // phase A: wave 0 decides
        int r = rows0 + tid;
        float gm1 = m1p[r], gm2 = m2p[r];
        int gbi = bip[r];
        {
            size_t idx = (size_t)N + r;  // KS == 2, slice 1
            float m1b = m1p[idx], m2b = m2p[idx];
            int bb = bip[idx];
            // higher slice = higher codes: strictly greater only (first-min)
            bool take = m1b > gm1;
            gm2 = fmaxf(fminf(gm1, m1b), fmaxf(gm2, m2b));
            gm1 = take ? m1b : gm1;
            gbi = take ? bb : gbi;
        }
        bool amb = 2.0f * (gm1 - gm2) < MARGIN;
        // one u32 atomic per block for the ambiguous list (ballot + rank)
        unsigned long long mask = __ballot(amb);
        int cnt = __popcll(mask);
        unsigned base = 0;
        if (tid == 0 && cnt) base = atomicAdd(nunc, (unsigned)cnt);
        base = __shfl(base, 0);
        int dec = gbi;
        double lpart = 0.0;
        if (amb) {
            int rank = __popcll(mask & ((1ull << tid) - 1ull));
            list[base + rank] = (unsigned)r;
            dec = -1;
        } else {
            outidx[r] = (float)dec;
            // ||x-e||^2 = xx + ee - 2*dot = xx - 2*m1  (m1 = dot - ee/2)
            lpart = (double)(xxp[r] - 2.0f * gm1);
        }
        sdec[tid] = dec;
#pragma unroll
        for (int off = 32; off; off >>= 1) lpart += __shfl_down(lpart, off);
        if (tid == 0) lossA[blockIdx.x] = lpart;  // plain store, no atomic
    }
    __syncthreads();

    // phase B: quantized gather-write; each wave stores 1KB contiguous/pass
    const int chunk = tid & 15, rl = tid >> 4;  // 16 rows x 16 chunks
#pragma unroll
    for (int p = 0; p < 4; ++p) {
        int lr = p * 16 + rl;
        int dp = sdec[lr];
        if (dp >= 0) {
            float4 ev = *(const float4*)(emb + (size_t)dp * D + chunk * 4);
            *(float4*)(outq + (size_t)(rows0 + lr) * D + chunk * 4) = ev;
        }
    }
}

// one WAVE per ambiguous row: np-f32-exact argmin, eT-coalesced
__global__ __launch_bounds__(256) void vq_resolve(
    const float* __restrict__ x, const float* __restrict__ emb,
    const float* __restrict__ eT, const float* __restrict__ eenp,
    int N, int K,
    float* __restrict__ outq, float* __restrict__ outidx,
    double* __restrict__ lossR,
    const unsigned* __restrict__ nunc, const unsigned* __restrict__ list) {
    const unsigned n = *nunc;
    const int w = threadIdx.x >> 6, lane = threadIdx.x & 63;
    const f32x4* eT4 = (const f32x4*)eT;  // [D][K/4]
    double lp = 0.0;
    for (unsigned i = blockIdx.x * 4 + w; i < n; i += gridDim.x * 4) {
        const int r = (int)list[i];
        // full x row per lane (same-address broadcast loads, L1-hot)
        float xr[D];
        {
            const float4* xp = (const float4*)(x + (size_t)r * D);
#pragma unroll
            for (int jj = 0; jj < D / 4; ++jj) {
                float4 v = xp[jj];
                xr[4 * jj + 0] = v.x; xr[4 * jj + 1] = v.y;
                xr[4 * jj + 2] = v.z; xr[4 * jj + 3] = v.w;
            }
        }
        float xx = np_pairwise_sumsq64(xr);
        // lane owns codes k = kk*256 + lane*4 + jj; np-exact sequential-d
        f32x4 dt[4];
#pragma unroll
        for (int kk = 0; kk < 4; ++kk) dt[kk] = (f32x4){0.f, 0.f, 0.f, 0.f};
#pragma unroll 4
        for (int d = 0; d < D; ++d) {
            float xv = xr[d];
#pragma unroll
            for (int kk = 0; kk < 4; ++kk) {
                f32x4 ev = eT4[(size_t)d * 256 + kk * 64 + lane];
                dt[kk][0] = __fmaf_rn(xv, ev[0], dt[kk][0]);
                dt[kk][1] = __fmaf_rn(xv, ev[1], dt[kk][1]);
                dt[kk][2] = __fmaf_rn(xv, ev[2], dt[kk][2]);
                dt[kk][3] = __fmaf_rn(xv, ev[3], dt[kk][3]);
            }
        }
        float bm = 1e30f;
        int bi = 0;
#pragma unroll
        for (int kk = 0; kk < 4; ++kk)
#pragma unroll
            for (int jj = 0; jj < 4; ++jj) {
                int k = kk * 256 + lane * 4 + jj;  // ascending within lane
                float dist = __fsub_rn(__fadd_rn(xx, eenp[k]),
                                       __fmul_rn(2.0f, dt[kk][jj]));
                if (dist < bm) { bm = dist; bi = k; }
            }
        // wave argmin, ties -> lowest index (numpy first-occurrence)
#pragma unroll
        for (int off = 1; off < 64; off <<= 1) {
            float ov = __shfl_xor(bm, off);
            int oi = __shfl_xor(bi, off);
            if (ov < bm || (ov == bm && oi < bi)) { bm = ov; bi = oi; }
        }
        float ev = emb[(size_t)bi * D + lane];
        outq[(size_t)r * D + lane] = ev;
        if (lane == 0) {
            outidx[r] = (float)bi;
            lp += (double)bm;  // bm = ||x-e||^2 (np-f32)
        }
    }
    __shared__ double lsw[4];
    if (lane == 0) lsw[w] = lp;
    __syncthreads();
    if (threadIdx.x == 0)
        lossR[blockIdx.x] = lsw[0] + lsw[1] + lsw[2] + lsw[3];  // plain store
}

// histogram of outidx via LDS (16 fat blocks) + last-block finalize
__global__ __launch_bounds__(256) void vq_histperp(
    const float* __restrict__ outidx, int N, int K,
    unsigned* __restrict__ counts, unsigned* __restrict__ done,
    const double* __restrict__ lossA, int nA,
    const double* __restrict__ lossR, int nR,
    float* __restrict__ out_loss, float* __restrict__ out_perp) {
    __shared__ unsigned h[1024];
    __shared__ unsigned rank_s;
#pragma unroll
    for (int i = 0; i < 4; ++i) h[threadIdx.x + 256 * i] = 0;
    __syncthreads();
    int per = N / gridDim.x;
    int base = blockIdx.x * per;
    for (int i = threadIdx.x; i < per; i += 256) {
        int k = (int)outidx[base + i];
        atomicAdd(&h[k], 1u);
    }
    __syncthreads();
#pragma unroll
    for (int i = 0; i < 4; ++i) {
        int b = threadIdx.x + 256 * i;
        unsigned v = h[b];
        if (b < K && v) atomicAdd(counts + b, v);
    }
    __threadfence();
    if (threadIdx.x == 0) rank_s = atomicAdd(done, 1u);
    __syncthreads();
    if (rank_s == gridDim.x - 1) {  // last block: counts complete
        double part = 0.0;
        for (int k = threadIdx.x; k < K; k += 256) {
            // device-scope atomic read (cross-XCD-safe)
            unsigned c = atomicAdd(counts + k, 0u);
            double p = (double)c / (double)N;
            part += p * log(p + 1e-10);
        }
        double lsum = 0.0;
        for (int i = threadIdx.x; i < nA; i += 256) lsum += lossA[i];
        for (int i = threadIdx.x; i < nR; i += 256) lsum += lossR[i];
#pragma unroll
        for (int off = 32; off; off >>= 1) {
            part += __shfl_down(part, off);
            lsum += __shfl_down(lsum, off);
        }
        __shared__ double ls[4], ls2[4];
        if ((threadIdx.x & 63) == 0) {
            ls[threadIdx.x >> 6] = part;
            ls2[threadIdx.x >> 6] = lsum;
        }
        __syncthreads();
        if (threadIdx.x == 0) {
            double s = ls[0] + ls[1] + ls[2] + ls[3];
            double L = ls2[0] + ls2[1] + ls2[2] + ls2[3];
            *out_perp = (float)exp(-s);
            *out_loss = (float)(1.25 * (L / ((double)N * (double)D)));
        }
    }
}

extern "C" void kernel_launch(void* const* d_in, const int* in_sizes, int n_in,
                              void* d_out, int out_size, void* d_ws, size_t ws_size,
                              hipStream_t stream) {
    const float* x = (const float*)d_in[0];
    const float* emb = (const float*)d_in[1];
    int N = in_sizes[0] / D;
    int K = in_sizes[1] / D;

    float* outq = (float*)d_out;
    float* out_loss = outq + (size_t)N * D;
    float* outidx = out_loss + 1;
    float* out_perp = outidx + N;

    char* ws = (char*)d_ws;
    unsigned* counts = (unsigned*)ws;                          // K*4
    unsigned* done = (unsigned*)(ws + (size_t)K * 4);          // 4
    unsigned* nunc = (unsigned*)(ws + (size_t)K * 4 + 4);     // 4 (+8 pad)
    size_t off = (size_t)K * 4 + 16;
    float* neh = (float*)(ws + off);            off += (size_t)K * 4;
    float* eenp = (float*)(ws + off);           off += (size_t)K * 4;
    unsigned short* ehs = (unsigned short*)(ws + off);  off += (size_t)K * 256;
    float* eT = (float*)(ws + off);              off += (size_t)K * D * 4;
    float* m1p = (float*)(ws + off);             off += (size_t)KS * N * 4;
    float* m2p = (float*)(ws + off);             off += (size_t)KS * N * 4;
    int* bip = (int*)(ws + off);                 off += (size_t)KS * N * 4;
    float* xxp = (float*)(ws + off);             off += (size_t)N * 4;
    unsigned* list = (unsigned*)(ws + off);      off += (size_t)N * 4;
    int nA = N / 64, nR = 1024;
    double* lossA = (double*)(ws + off);         off += (size_t)nA * 8;
    double* lossR = (double*)(ws + off);         off += (size_t)nR * 8;

    hipMemsetAsync(d_ws, 0, (size_t)K * 4 + 16, stream);  // counts+done+nunc

    // prep: 64 blocks ehs, 4 blocks sums, 256 blocks eT
    vq_prep_all<<<64 + 4 + (K * D + 255) / 256, 256, 0, stream>>>(
        emb, K, eenp, neh, ehs, eT);
    vq_screen<<<(N / 256) * KS, 256, 0, stream>>>(x, ehs, neh, N, K,
                                                  m1p, m2p, bip, xxp);
    vq_epilogue<<<N / 64, 256, 0, stream>>>(emb, m1p, m2p, bip, xxp, N,
                                            outq, outidx, lossA, nunc, list);
    vq_resolve<<<1024, 256, 0, stream>>>(x, emb, eT, eenp, N, K,
                                         outq, outidx, lossR, nunc, list);
    vq_histperp<<<16, 256, 0, stream>>>(outidx, N, K, counts, done,
                                        lossA, nA, lossR, nR,
                                        out_loss, out_perp);
}

// Round 15
// 185.475 us; speedup vs baseline: 1.0246x; 1.0246x over previous
//
#include <hip/hip_runtime.h>
#include <hip/hip_bf16.h>

#define D 64
#define MARGIN 4e-5f
#define KS 2          // k-split factor across blocks

typedef __attribute__((ext_vector_type(8))) short bf16x8;
typedef __attribute__((ext_vector_type(4))) float f32x4;
typedef __attribute__((ext_vector_type(4))) unsigned uint4v;

// ---------------------------------------------------------------------------
// VectorQuantizer. Harness ref = numpy-f32 recompute; argmin must bit-match
// np-f32 (xx pairwise-8 sum, sequential-d FMA sgemm, first-min). Screen is a
// split-bf16 MFMA proxy: acc = dot - ee/2 (6-MFMA chain seeded C = -ee/2),
// argmax(acc) == argmin(dist). Codes tile-major pre-permuted, LDS-staged
// double-buffered (T14 split) -> 1 VMEM/wave/tile. Screen emits per-slice
// (m1,m2,bi) SoA planes + xxp. vq_epilogue (2048 blocks x 64 rows): decide
// (ascending slice + strict > == np first-min, margin test), idx, block-
// partial loss -> lossA[] (plain store; fp atomicAdd = CAS loop, R13 lesson),
// ambiguous list via one u32 atomic per block (ballot+rank), coalesced
// quantized write. vq_resolve: one WAVE per ambiguous row, NO per-lane row
// array (R14 lesson: xr[64] spilled to scratch -> 70MB scratch traffic,
// 82us); x row read as wave-uniform scalar loads fused with np-exact
// pairwise-8 sumsq (rs[8] zero-init: 0+a^2==a^2 exactly). vq_histperp:
// LDS hist of outidx + last-block reduce(lossA,lossR) + perplexity/loss.
// d_out (float): quantized[N*D] | loss[1] | indices[N] | perplexity[1]
// ws: counts u32[K] | done u32 | nunc u32 | pad | neh f32[K] | eenp f32[K]
//     | ehs bf16-tiles[K*256B] | eT f32[D*K]
//     | m1p f32[KS*N] | m2p f32[KS*N] | bip i32[KS*N] | xxp f32[N]
//     | list u32[N] | lossA f64[2048] | lossR f64[1024]
// ---------------------------------------------------------------------------

__device__ __forceinline__ float np_pairwise_sumsq64(const float* a) {
    float r[8];
#pragma unroll
    for (int j = 0; j < 8; ++j) r[j] = __fmul_rn(a[j], a[j]);
#pragma unroll
    for (int i = 8; i < 64; i += 8)
#pragma unroll
        for (int j = 0; j < 8; ++j)
            r[j] = __fadd_rn(r[j], __fmul_rn(a[i + j], a[i + j]));
    return __fadd_rn(
        __fadd_rn(__fadd_rn(r[0], r[1]), __fadd_rn(r[2], r[3])),
        __fadd_rn(__fadd_rn(r[4], r[5]), __fadd_rn(r[6], r[7])));
}

#define CVT8(F0, F1, H, L)                                                    \
    do {                                                                      \
        float _f[8] = {F0.x, F0.y, F0.z, F0.w, F1.x, F1.y, F1.z, F1.w};       \
        _Pragma("unroll") for (int _i = 0; _i < 8; ++_i) {                    \
            unsigned _u = __float_as_uint(_f[_i]);                            \
            unsigned _hb = (_u + 0x7fffu + ((_u >> 16) & 1u)) >> 16;          \
            float _hf = __uint_as_float(_hb << 16);                           \
            float _r = _f[_i] - _hf;                                          \
            unsigned _u2 = __float_as_uint(_r);                               \
            unsigned _lb = (_u2 + 0x7fffu + ((_u2 >> 16) & 1u)) >> 16;        \
            H[_i] = (short)_hb;                                               \
            L[_i] = (short)_lb;                                               \
        }                                                                     \
    } while (0)

// prep: blocks [0,64) build ehs tile-major; [64,68) sumsq; [68,324) eT
__global__ __launch_bounds__(256) void vq_prep_all(
    const float* __restrict__ emb, int K,
    float* __restrict__ eenp, float* __restrict__ neh,
    unsigned short* __restrict__ ehs, float* __restrict__ eT) {
    int b = blockIdx.x;
    if (b < 64) {
        int t = b * 256 + threadIdx.x;     // (tile, sec, lane): 16384 frags
        int tile = t >> 8, r = t & 255, s = r >> 6, l = r & 63;
        int sub = l & 15, grp = l >> 4;
        int k = tile * 16 + sub;
        int d0 = ((s & 1) << 5) + (grp << 3);
        const float* e = emb + (size_t)k * D + d0;
        float4 f0 = *(const float4*)e;
        float4 f1 = *(const float4*)(e + 4);
        bf16x8 h, lo;
        CVT8(f0, f1, h, lo);
        *(bf16x8*)(ehs + (size_t)t * 8) = (s >> 1) ? lo : h;  // s0,s1=eh s2,s3=el
    } else if (b < 68) {
        int k = (b - 64) * 256 + threadIdx.x;   // 1024 codes
        float s = np_pairwise_sumsq64(emb + (size_t)k * D);
        eenp[k] = s;
        neh[k] = -0.5f * s;
    } else {
        int t = (b - 68) * 256 + threadIdx.x;   // 65536 = D*K, coalesced write
        int d = t / K, k = t - d * K;
        eT[t] = emb[(size_t)k * D + d];
    }
}

__global__ __launch_bounds__(256) void vq_screen(
    const float* __restrict__ x, const unsigned short* __restrict__ ehs,
    const float* __restrict__ neh, int N, int K,
    float* __restrict__ m1p, float* __restrict__ m2p, int* __restrict__ bip,
    float* __restrict__ xxp) {
    const int tid = threadIdx.x;
    const int lane = tid & 63;
    const int wid = tid >> 6;
    const int kslice = blockIdx.x & (KS - 1);
    const int rowblk = blockIdx.x >> 1;  // KS == 2
    const int row0 = rowblk * 256 + wid * 64;  // 64 rows/wave
    const int sub = lane & 15, grp = lane >> 4;
    const int g4 = grp << 2;
    const int k0 = kslice * (K / KS);
    const int NT = (K / KS) >> 4;        // 16-code tiles in this slice
    const int t0 = k0 >> 4;

    __shared__ __align__(16) unsigned short lds[2][2048];  // 2 bufs x 4KB

    // persistent B frags: x rows, split bf16, 4 row-tiles x 2 k-slices.
    // Also accumulate per-lane sumsq (loss-only, f32) and grp-reduce -> xx.
    bf16x8 xh[4][2], xl[4][2];
    float xq[4];
#pragma unroll
    for (int rt = 0; rt < 4; ++rt) {
        xq[rt] = 0.f;
        const float* xrow = x + (((size_t)(row0 + (rt << 4) + sub)) << 6) + (grp << 3);
#pragma unroll
        for (int s = 0; s < 2; ++s) {
            float4 f0 = *(const float4*)(xrow + (s << 5));
            float4 f1 = *(const float4*)(xrow + (s << 5) + 4);
            xq[rt] = fmaf(f0.x, f0.x, xq[rt]); xq[rt] = fmaf(f0.y, f0.y, xq[rt]);
            xq[rt] = fmaf(f0.z, f0.z, xq[rt]); xq[rt] = fmaf(f0.w, f0.w, xq[rt]);
            xq[rt] = fmaf(f1.x, f1.x, xq[rt]); xq[rt] = fmaf(f1.y, f1.y, xq[rt]);
            xq[rt] = fmaf(f1.z, f1.z, xq[rt]); xq[rt] = fmaf(f1.w, f1.w, xq[rt]);
            CVT8(f0, f1, xh[rt][s], xl[rt][s]);
        }
    }
#pragma unroll
    for (int rt = 0; rt < 4; ++rt) {
        xq[rt] += __shfl_xor(xq[rt], 16);
        xq[rt] += __shfl_xor(xq[rt], 32);  // all grps summed; lane<16 = row xx
    }

    float m1[4], m2[4];
    int bi[4];
#pragma unroll
    for (int rt = 0; rt < 4; ++rt) { m1[rt] = -3e38f; m2[rt] = -3e38f; bi[rt] = 0; }

    // staging: this thread's 16B slot (wave wid stages section wid)
    const unsigned short* sbase = ehs + ((size_t)t0 << 11);  // tile stride 2048 ush
    const int slot = (wid << 9) + (lane << 3);               // ushort offset

    uint4v tmp = *(const uint4v*)(sbase + slot);             // tile 0
    *(uint4v*)&lds[0][slot] = tmp;
    __syncthreads();

    for (int t = 0; t < NT; ++t) {
        const int cur = t & 1;
        if (t + 1 < NT)  // T14: issue next-tile load before compute
            tmp = *(const uint4v*)(sbase + ((size_t)(t + 1) << 11) + slot);

        f32x4 cb = *(const f32x4*)(neh + k0 + (t << 4) + g4);
        const bf16x8* L = (const bf16x8*)&lds[cur][0];
        bf16x8 a0 = L[lane];        // eh d[0,32)
        bf16x8 a1 = L[64 + lane];   // eh d[32,64)
        bf16x8 a2 = L[128 + lane];  // el d[0,32)
        bf16x8 a3 = L[192 + lane];  // el d[32,64)

        f32x4 acc[4];
#pragma unroll
        for (int rt = 0; rt < 4; ++rt)
            acc[rt] = __builtin_amdgcn_mfma_f32_16x16x32_bf16(a0, xh[rt][0], cb, 0, 0, 0);
#pragma unroll
        for (int rt = 0; rt < 4; ++rt)
            acc[rt] = __builtin_amdgcn_mfma_f32_16x16x32_bf16(a2, xh[rt][0], acc[rt], 0, 0, 0);
#pragma unroll
        for (int rt = 0; rt < 4; ++rt)
            acc[rt] = __builtin_amdgcn_mfma_f32_16x16x32_bf16(a0, xl[rt][0], acc[rt], 0, 0, 0);
#pragma unroll
        for (int rt = 0; rt < 4; ++rt)
            acc[rt] = __builtin_amdgcn_mfma_f32_16x16x32_bf16(a1, xh[rt][1], acc[rt], 0, 0, 0);
#pragma unroll
        for (int rt = 0; rt < 4; ++rt)
            acc[rt] = __builtin_amdgcn_mfma_f32_16x16x32_bf16(a3, xh[rt][1], acc[rt], 0, 0, 0);
#pragma unroll
        for (int rt = 0; rt < 4; ++rt)
            acc[rt] = __builtin_amdgcn_mfma_f32_16x16x32_bf16(a1, xl[rt][1], acc[rt], 0, 0, 0);

        // top-2 update; per-lane codes ascend -> np first-min
        int cbase = k0 + (t << 4) + g4;
#pragma unroll
        for (int rt = 0; rt < 4; ++rt) {
#pragma unroll
            for (int j = 0; j < 4; ++j) {
                float v = acc[rt][j];
                int c = cbase + j;
                bool tk = v > m1[rt];
                m2[rt] = fminf(fmaxf(v, m2[rt]), m1[rt]);  // med3(v,m2,m1)
                m1[rt] = tk ? v : m1[rt];
                bi[rt] = tk ? c : bi[rt];
            }
        }

        if (t + 1 < NT)  // T14: write-late into the other buffer
            *(uint4v*)&lds[cur ^ 1][slot] = tmp;
        __syncthreads();
    }

    // merge the 4 code-groups (lanes sub, sub+16, sub+32, sub+48)
#pragma unroll
    for (int rt = 0; rt < 4; ++rt) {
#pragma unroll
        for (int off = 16; off <= 32; off <<= 1) {
            float om1 = __shfl_xor(m1[rt], off);
            float om2 = __shfl_xor(m2[rt], off);
            int obi = __shfl_xor(bi[rt], off);
            bool take = (om1 > m1[rt]) || (om1 == m1[rt] && obi < bi[rt]);
            m2[rt] = fmaxf(fminf(om1, m1[rt]), fmaxf(om2, m2[rt]));
            m1[rt] = take ? om1 : m1[rt];
            bi[rt] = take ? obi : bi[rt];
        }
    }

    // emit coalesced SoA planes (lanes 0-15 own 16 consecutive rows per rt)
    if (lane < 16) {
#pragma unroll
        for (int rt = 0; rt < 4; ++rt) {
            size_t idx = (size_t)kslice * N + row0 + (rt << 4) + lane;
            m1p[idx] = m1[rt];
            m2p[idx] = m2[rt];
            bip[idx] = bi[rt];
            if (kslice == 0) xxp[row0 + (rt << 4) + lane] = xq[rt];
        }
    }
}

// decide + idx + block-partial loss (plain store) + coalesced quantized write
__global__ __launch_bounds__(256) void vq_epilogue(
    const float* __restrict__ emb,
    const float* __restrict__ m1p, const float* __restrict__ m2p,
    const int* __restrict__ bip, const float* __restrict__ xxp, int N,
    float* __restrict__ outq, float* __restrict__ outidx,
    double* __restrict__ lossA,
    unsigned* __restrict__ nunc, unsigned* __restrict__ list) {
    const int tid = threadIdx.x;
    const int rows0 = blockIdx.x * 64;
    __shared__ int sdec[64];

    if (tid < 64) {  // phase A: wave 0 decides
        int r = rows0 + tid;
        float gm1 = m1p[r], gm2 = m2p[r];
        int gbi = bip[r];
        {
            size_t idx = (size_t)N + r;  // KS == 2, slice 1
            float m1b = m1p[idx], m2b = m2p[idx];
            int bb = bip[idx];
            // higher slice = higher codes: strictly greater only (first-min)
            bool take = m1b > gm1;
            gm2 = fmaxf(fminf(gm1, m1b), fmaxf(gm2, m2b));
            gm1 = take ? m1b : gm1;
            gbi = take ? bb : gbi;
        }
        bool amb = 2.0f * (gm1 - gm2) < MARGIN;
        // one u32 atomic per block for the ambiguous list (ballot + rank)
        unsigned long long mask = __ballot(amb);
        int cnt = __popcll(mask);
        unsigned base = 0;
        if (tid == 0 && cnt) base = atomicAdd(nunc, (unsigned)cnt);
        base = __shfl(base, 0);
        int dec = gbi;
        double lpart = 0.0;
        if (amb) {
            int rank = __popcll(mask & ((1ull << tid) - 1ull));
            list[base + rank] = (unsigned)r;
            dec = -1;
        } else {
            outidx[r] = (float)dec;
            // ||x-e||^2 = xx + ee - 2*dot = xx - 2*m1  (m1 = dot - ee/2)
            lpart = (double)(xxp[r] - 2.0f * gm1);
        }
        sdec[tid] = dec;
#pragma unroll
        for (int off = 32; off; off >>= 1) lpart += __shfl_down(lpart, off);
        if (tid == 0) lossA[blockIdx.x] = lpart;  // plain store, no atomic
    }
    __syncthreads();

    // phase B: quantized gather-write; each wave stores 1KB contiguous/pass
    const int chunk = tid & 15, rl = tid >> 4;  // 16 rows x 16 chunks
#pragma unroll
    for (int p = 0; p < 4; ++p) {
        int lr = p * 16 + rl;
        int dp = sdec[lr];
        if (dp >= 0) {
            float4 ev = *(const float4*)(emb + (size_t)dp * D + chunk * 4);
            *(float4*)(outq + (size_t)(rows0 + lr) * D + chunk * 4) = ev;
        }
    }
}

// one WAVE per ambiguous row: np-f32-exact argmin, eT-coalesced.
// NO per-lane row array (scratch-spill, R14); x read as wave-uniform scalar
// loads, np-exact pairwise-8 sumsq fused into the d-loop (rs zero-init:
// 0.0f + a*a == a*a exactly for squares).
__global__ __launch_bounds__(256) void vq_resolve(
    const float* __restrict__ x, const float* __restrict__ emb,
    const float* __restrict__ eT, const float* __restrict__ eenp,
    int N, int K,
    float* __restrict__ outq, float* __restrict__ outidx,
    double* __restrict__ lossR,
    const unsigned* __restrict__ nunc, const unsigned* __restrict__ list) {
    const unsigned n = *nunc;
    const int w = threadIdx.x >> 6, lane = threadIdx.x & 63;
    const f32x4* eT4 = (const f32x4*)eT;  // [D][K/4]
    double lp = 0.0;
    for (unsigned i = blockIdx.x * 4 + w; i < n; i += gridDim.x * 4) {
        const int r = (int)list[i];
        const float* xrow = x + (size_t)r * D;
        f32x4 dt[4];
        float rs[8];
#pragma unroll
        for (int kk = 0; kk < 4; ++kk) dt[kk] = (f32x4){0.f, 0.f, 0.f, 0.f};
#pragma unroll
        for (int j = 0; j < 8; ++j) rs[j] = 0.f;
#pragma unroll 8
        for (int d = 0; d < D; ++d) {
            float xv = xrow[d];  // wave-uniform scalar load, row L1-hot
            rs[d & 7] = __fadd_rn(rs[d & 7], __fmul_rn(xv, xv));
#pragma unroll
            for (int kk = 0; kk < 4; ++kk) {
                f32x4 ev = eT4[(size_t)d * 256 + kk * 64 + lane];
                dt[kk][0] = __fmaf_rn(xv, ev[0], dt[kk][0]);
                dt[kk][1] = __fmaf_rn(xv, ev[1], dt[kk][1]);
                dt[kk][2] = __fmaf_rn(xv, ev[2], dt[kk][2]);
                dt[kk][3] = __fmaf_rn(xv, ev[3], dt[kk][3]);
            }
        }
        // np pairwise-8 final combine (exact tree)
        float xx = __fadd_rn(
            __fadd_rn(__fadd_rn(rs[0], rs[1]), __fadd_rn(rs[2], rs[3])),
            __fadd_rn(__fadd_rn(rs[4], rs[5]), __fadd_rn(rs[6], rs[7])));
        float bm = 1e30f;
        int bi = 0;
#pragma unroll
        for (int kk = 0; kk < 4; ++kk)
#pragma unroll
            for (int jj = 0; jj < 4; ++jj) {
                int k = kk * 256 + lane * 4 + jj;  // ascending within lane
                float dist = __fsub_rn(__fadd_rn(xx, eenp[k]),
                                       __fmul_rn(2.0f, dt[kk][jj]));
                if (dist < bm) { bm = dist; bi = k; }
            }
        // wave argmin, ties -> lowest index (numpy first-occurrence)
#pragma unroll
        for (int off = 1; off < 64; off <<= 1) {
            float ov = __shfl_xor(bm, off);
            int oi = __shfl_xor(bi, off);
            if (ov < bm || (ov == bm && oi < bi)) { bm = ov; bi = oi; }
        }
        float ev = emb[(size_t)bi * D + lane];
        outq[(size_t)r * D + lane] = ev;
        if (lane == 0) {
            outidx[r] = (float)bi;
            lp += (double)bm;  // bm = ||x-e||^2 (np-f32)
        }
    }
    __shared__ double lsw[4];
    if (lane == 0) lsw[w] = lp;
    __syncthreads();
    if (threadIdx.x == 0)
        lossR[blockIdx.x] = lsw[0] + lsw[1] + lsw[2] + lsw[3];  // plain store
}

// histogram of outidx via LDS (16 fat blocks) + last-block finalize
__global__ __launch_bounds__(256) void vq_histperp(
    const float* __restrict__ outidx, int N, int K,
    unsigned* __restrict__ counts, unsigned* __restrict__ done,
    const double* __restrict__ lossA, int nA,
    const double* __restrict__ lossR, int nR,
    float* __restrict__ out_loss, float* __restrict__ out_perp) {
    __shared__ unsigned h[1024];
    __shared__ unsigned rank_s;
#pragma unroll
    for (int i = 0; i < 4; ++i) h[threadIdx.x + 256 * i] = 0;
    __syncthreads();
    int per = N / gridDim.x;
    int base = blockIdx.x * per;
    for (int i = threadIdx.x; i < per; i += 256) {
        int k = (int)outidx[base + i];
        atomicAdd(&h[k], 1u);
    }
    __syncthreads();
#pragma unroll
    for (int i = 0; i < 4; ++i) {
        int b = threadIdx.x + 256 * i;
        unsigned v = h[b];
        if (b < K && v) atomicAdd(counts + b, v);
    }
    __threadfence();
    if (threadIdx.x == 0) rank_s = atomicAdd(done, 1u);
    __syncthreads();
    if (rank_s == gridDim.x - 1) {  // last block: counts complete
        double part = 0.0;
        for (int k = threadIdx.x; k < K; k += 256) {
            // device-scope atomic read (cross-XCD-safe)
            unsigned c = atomicAdd(counts + k, 0u);
            double p = (double)c / (double)N;
            part += p * log(p + 1e-10);
        }
        double lsum = 0.0;
        for (int i = threadIdx.x; i < nA; i += 256) lsum += lossA[i];
        for (int i = threadIdx.x; i < nR; i += 256) lsum += lossR[i];
#pragma unroll
        for (int off = 32; off; off >>= 1) {
            part += __shfl_down(part, off);
            lsum += __shfl_down(lsum, off);
        }
        __shared__ double ls[4], ls2[4];
        if ((threadIdx.x & 63) == 0) {
            ls[threadIdx.x >> 6] = part;
            ls2[threadIdx.x >> 6] = lsum;
        }
        __syncthreads();
        if (threadIdx.x == 0) {
            double s = ls[0] + ls[1] + ls[2] + ls[3];
            double L = ls2[0] + ls2[1] + ls2[2] + ls2[3];
            *out_perp = (float)exp(-s);
            *out_loss = (float)(1.25 * (L / ((double)N * (double)D)));
        }
    }
}

extern "C" void kernel_launch(void* const* d_in, const int* in_sizes, int n_in,
                              void* d_out, int out_size, void* d_ws, size_t ws_size,
                              hipStream_t stream) {
    const float* x = (const float*)d_in[0];
    const float* emb = (const float*)d_in[1];
    int N = in_sizes[0] / D;
    int K = in_sizes[1] / D;

    float* outq = (float*)d_out;
    float* out_loss = outq + (size_t)N * D;
    float* outidx = out_loss + 1;
    float* out_perp = outidx + N;

    char* ws = (char*)d_ws;
    unsigned* counts = (unsigned*)ws;                          // K*4
    unsigned* done = (unsigned*)(ws + (size_t)K * 4);          // 4
    unsigned* nunc = (unsigned*)(ws + (size_t)K * 4 + 4);     // 4 (+8 pad)
    size_t off = (size_t)K * 4 + 16;
    float* neh = (float*)(ws + off);            off += (size_t)K * 4;
    float* eenp = (float*)(ws + off);           off += (size_t)K * 4;
    unsigned short* ehs = (unsigned short*)(ws + off);  off += (size_t)K * 256;
    float* eT = (float*)(ws + off);              off += (size_t)K * D * 4;
    float* m1p = (float*)(ws + off);             off += (size_t)KS * N * 4;
    float* m2p = (float*)(ws + off);             off += (size_t)KS * N * 4;
    int* bip = (int*)(ws + off);                 off += (size_t)KS * N * 4;
    float* xxp = (float*)(ws + off);             off += (size_t)N * 4;
    unsigned* list = (unsigned*)(ws + off);      off += (size_t)N * 4;
    int nA = N / 64, nR = 1024;
    double* lossA = (double*)(ws + off);         off += (size_t)nA * 8;
    double* lossR = (double*)(ws + off);         off += (size_t)nR * 8;

    hipMemsetAsync(d_ws, 0, (size_t)K * 4 + 16, stream);  // counts+done+nunc

    // prep: 64 blocks ehs, 4 blocks sums, 256 blocks eT
    vq_prep_all<<<64 + 4 + (K * D + 255) / 256, 256, 0, stream>>>(
        emb, K, eenp, neh, ehs, eT);
    vq_screen<<<(N / 256) * KS, 256, 0, stream>>>(x, ehs, neh, N, K,
                                                  m1p, m2p, bip, xxp);
    vq_epilogue<<<N / 64, 256, 0, stream>>>(emb, m1p, m2p, bip, xxp, N,
                                            outq, outidx, lossA, nunc, list);
    vq_resolve<<<1024, 256, 0, stream>>>(x, emb, eT, eenp, N, K,
                                         outq, outidx, lossR, nunc, list);
    vq_histperp<<<16, 256, 0, stream>>>(outidx, N, K, counts, done,
                                        lossA, nA, lossR, nR,
                                        out_loss, out_perp);
}

// Round 16
// 164.376 us; speedup vs baseline: 1.1562x; 1.1284x over previous
//
#include <hip/hip_runtime.h>
#include <hip/hip_bf16.h>

#define D 64
#define MARGIN 4e-5f
#define KS 2          // k-split factor across blocks

typedef __attribute__((ext_vector_type(8))) short bf16x8;
typedef __attribute__((ext_vector_type(4))) float f32x4;
typedef __attribute__((ext_vector_type(4))) unsigned uint4v;

// ---------------------------------------------------------------------------
// VectorQuantizer. Harness ref = numpy-f32 recompute; argmin must bit-match
// np-f32 (xx pairwise-8 sum, sequential-d FMA sgemm, first-min). Screen is a
// split-bf16 MFMA proxy: acc = dot - ee/2 (6-MFMA chain seeded C = -ee/2),
// argmax(acc) == argmin(dist). Codes tile-major pre-permuted, LDS-staged
// double-buffered (T14 split) -> 1 VMEM/wave/tile. Screen emits per-slice
// (m1,m2,bi) SoA planes + xxp. vq_epilogue (2048 blocks x 64 rows): decide
// (ascending slice + strict > == np first-min, margin test), idx, loss;
// ambiguous rows resolved INLINE block-cooperatively (256 thr x 4 codes,
// eT-coalesced np-f32-exact chains, x row via LDS broadcast — no per-lane
// array [R14 spill lesson], ascending merges == np first-min); ZERO fp
// atomics (R13 lesson: f64 atomicAdd = CAS loop, ~25ns x 3.4K serialized =
// 85us) — one plain lossA[block] store; ambiguous compaction via
// ballot+rank (no atomics at all). Separate resolve kernel REMOVED (R15
// lesson: extra launch+drain boundary cost ~75us regardless of its work).
// vq_histperp: LDS hist of outidx + last-block reduce(lossA) + finalize.
// d_out (float): quantized[N*D] | loss[1] | indices[N] | perplexity[1]
// ws: counts u32[K] | done u32 | pad | neh f32[K] | eenp f32[K]
//     | ehs bf16-tiles[K*256B] | eT f32[D*K]
//     | m1p f32[KS*N] | m2p f32[KS*N] | bip i32[KS*N] | xxp f32[N]
//     | lossA f64[N/64]
// ---------------------------------------------------------------------------

__device__ __forceinline__ float np_pairwise_sumsq64(const float* a) {
    float r[8];
#pragma unroll
    for (int j = 0; j < 8; ++j) r[j] = __fmul_rn(a[j], a[j]);
#pragma unroll
    for (int i = 8; i < 64; i += 8)
#pragma unroll
        for (int j = 0; j < 8; ++j)
            r[j] = __fadd_rn(r[j], __fmul_rn(a[i + j], a[i + j]));
    return __fadd_rn(
        __fadd_rn(__fadd_rn(r[0], r[1]), __fadd_rn(r[2], r[3])),
        __fadd_rn(__fadd_rn(r[4], r[5]), __fadd_rn(r[6], r[7])));
}

#define CVT8(F0, F1, H, L)                                                    \
    do {                                                                      \
        float _f[8] = {F0.x, F0.y, F0.z, F0.w, F1.x, F1.y, F1.z, F1.w};       \
        _Pragma("unroll") for (int _i = 0; _i < 8; ++_i) {                    \
            unsigned _u = __float_as_uint(_f[_i]);                            \
            unsigned _hb = (_u + 0x7fffu + ((_u >> 16) & 1u)) >> 16;          \
            float _hf = __uint_as_float(_hb << 16);                           \
            float _r = _f[_i] - _hf;                                          \
            unsigned _u2 = __float_as_uint(_r);                               \
            unsigned _lb = (_u2 + 0x7fffu + ((_u2 >> 16) & 1u)) >> 16;        \
            H[_i] = (short)_hb;                                               \
            L[_i] = (short)_lb;                                               \
        }                                                                     \
    } while (0)

// prep: blocks [0,64) build ehs tile-major; [64,68) sumsq; [68,324) eT
__global__ __launch_bounds__(256) void vq_prep_all(
    const float* __restrict__ emb, int K,
    float* __restrict__ eenp, float* __restrict__ neh,
    unsigned short* __restrict__ ehs, float* __restrict__ eT) {
    int b = blockIdx.x;
    if (b < 64) {
        int t = b * 256 + threadIdx.x;     // (tile, sec, lane): 16384 frags
        int tile = t >> 8, r = t & 255, s = r >> 6, l = r & 63;
        int sub = l & 15, grp = l >> 4;
        int k = tile * 16 + sub;
        int d0 = ((s & 1) << 5) + (grp << 3);
        const float* e = emb + (size_t)k * D + d0;
        float4 f0 = *(const float4*)e;
        float4 f1 = *(const float4*)(e + 4);
        bf16x8 h, lo;
        CVT8(f0, f1, h, lo);
        *(bf16x8*)(ehs + (size_t)t * 8) = (s >> 1) ? lo : h;  // s0,s1=eh s2,s3=el
    } else if (b < 68) {
        int k = (b - 64) * 256 + threadIdx.x;   // 1024 codes
        float s = np_pairwise_sumsq64(emb + (size_t)k * D);
        eenp[k] = s;
        neh[k] = -0.5f * s;
    } else {
        int t = (b - 68) * 256 + threadIdx.x;   // 65536 = D*K, coalesced write
        int d = t / K, k = t - d * K;
        eT[t] = emb[(size_t)k * D + d];
    }
}

__global__ __launch_bounds__(256) void vq_screen(
    const float* __restrict__ x, const unsigned short* __restrict__ ehs,
    const float* __restrict__ neh, int N, int K,
    float* __restrict__ m1p, float* __restrict__ m2p, int* __restrict__ bip,
    float* __restrict__ xxp) {
    const int tid = threadIdx.x;
    const int lane = tid & 63;
    const int wid = tid >> 6;
    const int kslice = blockIdx.x & (KS - 1);
    const int rowblk = blockIdx.x >> 1;  // KS == 2
    const int row0 = rowblk * 256 + wid * 64;  // 64 rows/wave
    const int sub = lane & 15, grp = lane >> 4;
    const int g4 = grp << 2;
    const int k0 = kslice * (K / KS);
    const int NT = (K / KS) >> 4;        // 16-code tiles in this slice
    const int t0 = k0 >> 4;

    __shared__ __align__(16) unsigned short lds[2][2048];  // 2 bufs x 4KB

    // persistent B frags: x rows, split bf16, 4 row-tiles x 2 k-slices.
    // Also accumulate per-lane sumsq (loss-only, f32) and grp-reduce -> xx.
    bf16x8 xh[4][2], xl[4][2];
    float xq[4];
#pragma unroll
    for (int rt = 0; rt < 4; ++rt) {
        xq[rt] = 0.f;
        const float* xrow = x + (((size_t)(row0 + (rt << 4) + sub)) << 6) + (grp << 3);
#pragma unroll
        for (int s = 0; s < 2; ++s) {
            float4 f0 = *(const float4*)(xrow + (s << 5));
            float4 f1 = *(const float4*)(xrow + (s << 5) + 4);
            xq[rt] = fmaf(f0.x, f0.x, xq[rt]); xq[rt] = fmaf(f0.y, f0.y, xq[rt]);
            xq[rt] = fmaf(f0.z, f0.z, xq[rt]); xq[rt] = fmaf(f0.w, f0.w, xq[rt]);
            xq[rt] = fmaf(f1.x, f1.x, xq[rt]); xq[rt] = fmaf(f1.y, f1.y, xq[rt]);
            xq[rt] = fmaf(f1.z, f1.z, xq[rt]); xq[rt] = fmaf(f1.w, f1.w, xq[rt]);
            CVT8(f0, f1, xh[rt][s], xl[rt][s]);
        }
    }
#pragma unroll
    for (int rt = 0; rt < 4; ++rt) {
        xq[rt] += __shfl_xor(xq[rt], 16);
        xq[rt] += __shfl_xor(xq[rt], 32);  // all grps summed; lane<16 = row xx
    }

    float m1[4], m2[4];
    int bi[4];
#pragma unroll
    for (int rt = 0; rt < 4; ++rt) { m1[rt] = -3e38f; m2[rt] = -3e38f; bi[rt] = 0; }

    // staging: this thread's 16B slot (wave wid stages section wid)
    const unsigned short* sbase = ehs + ((size_t)t0 << 11);  // tile stride 2048 ush
    const int slot = (wid << 9) + (lane << 3);               // ushort offset

    uint4v tmp = *(const uint4v*)(sbase + slot);             // tile 0
    *(uint4v*)&lds[0][slot] = tmp;
    __syncthreads();

    for (int t = 0; t < NT; ++t) {
        const int cur = t & 1;
        if (t + 1 < NT)  // T14: issue next-tile load before compute
            tmp = *(const uint4v*)(sbase + ((size_t)(t + 1) << 11) + slot);

        f32x4 cb = *(const f32x4*)(neh + k0 + (t << 4) + g4);
        const bf16x8* L = (const bf16x8*)&lds[cur][0];
        bf16x8 a0 = L[lane];        // eh d[0,32)
        bf16x8 a1 = L[64 + lane];   // eh d[32,64)
        bf16x8 a2 = L[128 + lane];  // el d[0,32)
        bf16x8 a3 = L[192 + lane];  // el d[32,64)

        f32x4 acc[4];
#pragma unroll
        for (int rt = 0; rt < 4; ++rt)
            acc[rt] = __builtin_amdgcn_mfma_f32_16x16x32_bf16(a0, xh[rt][0], cb, 0, 0, 0);
#pragma unroll
        for (int rt = 0; rt < 4; ++rt)
            acc[rt] = __builtin_amdgcn_mfma_f32_16x16x32_bf16(a2, xh[rt][0], acc[rt], 0, 0, 0);
#pragma unroll
        for (int rt = 0; rt < 4; ++rt)
            acc[rt] = __builtin_amdgcn_mfma_f32_16x16x32_bf16(a0, xl[rt][0], acc[rt], 0, 0, 0);
#pragma unroll
        for (int rt = 0; rt < 4; ++rt)
            acc[rt] = __builtin_amdgcn_mfma_f32_16x16x32_bf16(a1, xh[rt][1], acc[rt], 0, 0, 0);
#pragma unroll
        for (int rt = 0; rt < 4; ++rt)
            acc[rt] = __builtin_amdgcn_mfma_f32_16x16x32_bf16(a3, xh[rt][1], acc[rt], 0, 0, 0);
#pragma unroll
        for (int rt = 0; rt < 4; ++rt)
            acc[rt] = __builtin_amdgcn_mfma_f32_16x16x32_bf16(a1, xl[rt][1], acc[rt], 0, 0, 0);

        // top-2 update; per-lane codes ascend -> np first-min
        int cbase = k0 + (t << 4) + g4;
#pragma unroll
        for (int rt = 0; rt < 4; ++rt) {
#pragma unroll
            for (int j = 0; j < 4; ++j) {
                float v = acc[rt][j];
                int c = cbase + j;
                bool tk = v > m1[rt];
                m2[rt] = fminf(fmaxf(v, m2[rt]), m1[rt]);  // med3(v,m2,m1)
                m1[rt] = tk ? v : m1[rt];
                bi[rt] = tk ? c : bi[rt];
            }
        }

        if (t + 1 < NT)  // T14: write-late into the other buffer
            *(uint4v*)&lds[cur ^ 1][slot] = tmp;
        __syncthreads();
    }

    // merge the 4 code-groups (lanes sub, sub+16, sub+32, sub+48)
#pragma unroll
    for (int rt = 0; rt < 4; ++rt) {
#pragma unroll
        for (int off = 16; off <= 32; off <<= 1) {
            float om1 = __shfl_xor(m1[rt], off);
            float om2 = __shfl_xor(m2[rt], off);
            int obi = __shfl_xor(bi[rt], off);
            bool take = (om1 > m1[rt]) || (om1 == m1[rt] && obi < bi[rt]);
            m2[rt] = fmaxf(fminf(om1, m1[rt]), fmaxf(om2, m2[rt]));
            m1[rt] = take ? om1 : m1[rt];
            bi[rt] = take ? obi : bi[rt];
        }
    }

    // emit coalesced SoA planes (lanes 0-15 own 16 consecutive rows per rt)
    if (lane < 16) {
#pragma unroll
        for (int rt = 0; rt < 4; ++rt) {
            size_t idx = (size_t)kslice * N + row0 + (rt << 4) + lane;
            m1p[idx] = m1[rt];
            m2p[idx] = m2[rt];
            bip[idx] = bi[rt];
            if (kslice == 0) xxp[row0 + (rt << 4) + lane] = xq[rt];
        }
    }
}

// decide + inline block-cooperative np-exact resolve + idx + loss (plain
// store, zero atomics) + coalesced quantized write. 64 rows/block.
__global__ __launch_bounds__(256) void vq_epilogue(
    const float* __restrict__ x, const float* __restrict__ emb,
    const float* __restrict__ eT, const float* __restrict__ eenp,
    const float* __restrict__ m1p, const float* __restrict__ m2p,
    const int* __restrict__ bip, const float* __restrict__ xxp, int N, int K,
    float* __restrict__ outq, float* __restrict__ outidx,
    double* __restrict__ lossA) {
    const int tid = threadIdx.x;
    const int rows0 = blockIdx.x * 64;
    __shared__ int sdec[64];
    __shared__ int samb[64];
    __shared__ int snamb;
    __shared__ float sxrow[64];
    __shared__ float swm[4];
    __shared__ int swi[4];

    double lacc = 0.0;  // only tid 0's copy is ultimately stored

    if (tid < 64) {  // phase A: wave 0 decides
        int r = rows0 + tid;
        float gm1 = m1p[r], gm2 = m2p[r];
        int gbi = bip[r];
        {
            size_t idx = (size_t)N + r;  // KS == 2, slice 1
            float m1b = m1p[idx], m2b = m2p[idx];
            int bb = bip[idx];
            // higher slice = higher codes: strictly greater only (first-min)
            bool take = m1b > gm1;
            gm2 = fmaxf(fminf(gm1, m1b), fmaxf(gm2, m2b));
            gm1 = take ? m1b : gm1;
            gbi = take ? bb : gbi;
        }
        bool amb = 2.0f * (gm1 - gm2) < MARGIN;
        unsigned long long mask = __ballot(amb);   // wave 0 only
        int dec = gbi;
        double lpart = 0.0;
        if (amb) {
            int rank = __popcll(mask & ((1ull << tid) - 1ull));
            samb[rank] = tid;   // compacted ambiguous local rows, no atomic
            dec = -1;
        } else {
            outidx[r] = (float)dec;
            // ||x-e||^2 = xx + ee - 2*dot = xx - 2*m1  (m1 = dot - ee/2)
            lpart = (double)(xxp[r] - 2.0f * gm1);
        }
        sdec[tid] = dec;
        if (tid == 0) snamb = __popcll(mask);
#pragma unroll
        for (int off = 32; off; off >>= 1) lpart += __shfl_down(lpart, off);
        if (tid == 0) lacc = lpart;
    }
    __syncthreads();

    // inline resolve: whole block per ambiguous row; 256 thr x 4 codes each.
    // np-f32-exact: xx pairwise-8 (LDS broadcast), sequential-d FMA chains,
    // ascending thread/wave order + strict < + idx tie-break = np first-min.
    const int namb = snamb;
    const int w = tid >> 6, l = tid & 63;
    const f32x4* eT4 = (const f32x4*)eT;  // [D][K/4]
    for (int j = 0; j < namb; ++j) {
        int lr = samb[j];
        int row = rows0 + lr;
        if (tid < 64) sxrow[tid] = x[(size_t)row * D + tid];
        __syncthreads();
        float xx = np_pairwise_sumsq64(sxrow);
        f32x4 dt = (f32x4){0.f, 0.f, 0.f, 0.f};
#pragma unroll 8
        for (int d = 0; d < D; ++d) {
            f32x4 ev = eT4[(size_t)d * 256 + tid];
            float xv = sxrow[d];
            dt[0] = __fmaf_rn(xv, ev[0], dt[0]);
            dt[1] = __fmaf_rn(xv, ev[1], dt[1]);
            dt[2] = __fmaf_rn(xv, ev[2], dt[2]);
            dt[3] = __fmaf_rn(xv, ev[3], dt[3]);
        }
        float bm = 1e30f;
        int bi = 0;
#pragma unroll
        for (int jj = 0; jj < 4; ++jj) {
            int k = (tid << 2) + jj;  // ascending within thread
            float dist = __fsub_rn(__fadd_rn(xx, eenp[k]),
                                   __fmul_rn(2.0f, dt[jj]));
            if (dist < bm) { bm = dist; bi = k; }
        }
#pragma unroll
        for (int off = 1; off < 64; off <<= 1) {
            float ov = __shfl_xor(bm, off);
            int oi = __shfl_xor(bi, off);
            if (ov < bm || (ov == bm && oi < bi)) { bm = ov; bi = oi; }
        }
        if (l == 0) { swm[w] = bm; swi[w] = bi; }
        __syncthreads();
        if (tid == 0) {  // cross-wave merge, ascending wave order
            float fm = swm[0];
            int fi = swi[0];
#pragma unroll
            for (int ww = 1; ww < 4; ++ww) {
                float ov = swm[ww];
                int oi = swi[ww];
                if (ov < fm || (ov == fm && oi < fi)) { fm = ov; fi = oi; }
            }
            sdec[lr] = fi;
            outidx[row] = (float)fi;
            lacc += (double)fm;  // fm = ||x-e||^2 (np-f32), no atomic
        }
        __syncthreads();
    }
    if (tid == 0) lossA[blockIdx.x] = lacc;  // single plain store per block

    // phase B: quantized gather-write; each wave stores 1KB contiguous/pass
    const int chunk = tid & 15, rl = tid >> 4;  // 16 rows x 16 chunks
#pragma unroll
    for (int p = 0; p < 4; ++p) {
        int lr = p * 16 + rl;
        int dp = sdec[lr];
        if (dp >= 0) {
            float4 ev = *(const float4*)(emb + (size_t)dp * D + chunk * 4);
            *(float4*)(outq + (size_t)(rows0 + lr) * D + chunk * 4) = ev;
        }
    }
}

// histogram of outidx via LDS (16 fat blocks) + last-block finalize
__global__ __launch_bounds__(256) void vq_histperp(
    const float* __restrict__ outidx, int N, int K,
    unsigned* __restrict__ counts, unsigned* __restrict__ done,
    const double* __restrict__ lossA, int nA,
    float* __restrict__ out_loss, float* __restrict__ out_perp) {
    __shared__ unsigned h[1024];
    __shared__ unsigned rank_s;
#pragma unroll
    for (int i = 0; i < 4; ++i) h[threadIdx.x + 256 * i] = 0;
    __syncthreads();
    int per = N / gridDim.x;
    int base = blockIdx.x * per;
    for (int i = threadIdx.x; i < per; i += 256) {
        int k = (int)outidx[base + i];
        atomicAdd(&h[k], 1u);
    }
    __syncthreads();
#pragma unroll
    for (int i = 0; i < 4; ++i) {
        int b = threadIdx.x + 256 * i;
        unsigned v = h[b];
        if (b < K && v) atomicAdd(counts + b, v);
    }
    __threadfence();
    if (threadIdx.x == 0) rank_s = atomicAdd(done, 1u);
    __syncthreads();
    if (rank_s == gridDim.x - 1) {  // last block: counts complete
        double part = 0.0;
        for (int k = threadIdx.x; k < K; k += 256) {
            // device-scope atomic read (cross-XCD-safe)
            unsigned c = atomicAdd(counts + k, 0u);
            double p = (double)c / (double)N;
            part += p * log(p + 1e-10);
        }
        double lsum = 0.0;
        for (int i = threadIdx.x; i < nA; i += 256) lsum += lossA[i];
#pragma unroll
        for (int off = 32; off; off >>= 1) {
            part += __shfl_down(part, off);
            lsum += __shfl_down(lsum, off);
        }
        __shared__ double ls[4], ls2[4];
        if ((threadIdx.x & 63) == 0) {
            ls[threadIdx.x >> 6] = part;
            ls2[threadIdx.x >> 6] = lsum;
        }
        __syncthreads();
        if (threadIdx.x == 0) {
            double s = ls[0] + ls[1] + ls[2] + ls[3];
            double L = ls2[0] + ls2[1] + ls2[2] + ls2[3];
            *out_perp = (float)exp(-s);
            *out_loss = (float)(1.25 * (L / ((double)N * (double)D)));
        }
    }
}

extern "C" void kernel_launch(void* const* d_in, const int* in_sizes, int n_in,
                              void* d_out, int out_size, void* d_ws, size_t ws_size,
                              hipStream_t stream) {
    const float* x = (const float*)d_in[0];
    const float* emb = (const float*)d_in[1];
    int N = in_sizes[0] / D;
    int K = in_sizes[1] / D;

    float* outq = (float*)d_out;
    float* out_loss = outq + (size_t)N * D;
    float* outidx = out_loss + 1;
    float* out_perp = outidx + N;

    char* ws = (char*)d_ws;
    unsigned* counts = (unsigned*)ws;                          // K*4
    unsigned* done = (unsigned*)(ws + (size_t)K * 4);          // 4 (+12 pad)
    size_t off = (size_t)K * 4 + 16;
    float* neh = (float*)(ws + off);            off += (size_t)K * 4;
    float* eenp = (float*)(ws + off);           off += (size_t)K * 4;
    unsigned short* ehs = (unsigned short*)(ws + off);  off += (size_t)K * 256;
    float* eT = (float*)(ws + off);              off += (size_t)K * D * 4;
    float* m1p = (float*)(ws + off);             off += (size_t)KS * N * 4;
    float* m2p = (float*)(ws + off);             off += (size_t)KS * N * 4;
    int* bip = (int*)(ws + off);                 off += (size_t)KS * N * 4;
    float* xxp = (float*)(ws + off);             off += (size_t)N * 4;
    int nA = N / 64;
    double* lossA = (double*)(ws + off);         off += (size_t)nA * 8;

    hipMemsetAsync(d_ws, 0, (size_t)K * 4 + 16, stream);  // counts + done

    // prep: 64 blocks ehs, 4 blocks sums, 256 blocks eT
    vq_prep_all<<<64 + 4 + (K * D + 255) / 256, 256, 0, stream>>>(
        emb, K, eenp, neh, ehs, eT);
    vq_screen<<<(N / 256) * KS, 256, 0, stream>>>(x, ehs, neh, N, K,
                                                  m1p, m2p, bip, xxp);
    vq_epilogue<<<N / 64, 256, 0, stream>>>(x, emb, eT, eenp, m1p, m2p, bip,
                                            xxp, N, K, outq, outidx, lossA);
    vq_histperp<<<16, 256, 0, stream>>>(outidx, N, K, counts, done,
                                        lossA, nA, out_loss, out_perp);
}